// Round 8
// baseline (63.520 us; speedup 1.0000x reference)
//
#include <hip/hip_runtime.h>
#include <math.h>

#define C 128
#define NW 16        // waves per block
#define NT 1024      // threads per block
#define WIN 8192     // bounds-scan window (positions); >=10 sigma margin

typedef float f32x4 __attribute__((ext_vector_type(4)));

// Single fused kernel: one 1024-thread block (16 waves) per group.
// Prologue: (1) windowed scan of sorted `groups` for [lo,hi); (2) in-block
// 128x128 GEMV -> attn_vec; (3) PREFETCH of each wave's first stream tile,
// issued before the attnv finalize so tile-0 HBM latency hides behind it.
// Main: rotated streaming online-softmax loop (compute, then load next).
__global__ __launch_bounds__(NT, 8)
void k_attn(const float* __restrict__ node,
            const float* __restrict__ latent,
            const float* __restrict__ attn_w,
            const float* __restrict__ w_w,
            const float* __restrict__ w_b,
            const float* __restrict__ f1_w,
            const float* __restrict__ f1_b,
            const float* __restrict__ f2_w,
            const float* __restrict__ f2_b,
            const int* __restrict__ groups, int n,
            float* __restrict__ out) {
    const int g = blockIdx.x;
    const int B = gridDim.x;
    const int tid = threadIdx.x;
    const int lane = tid & 63;
    const int wv = tid >> 6;   // 0..15

    __shared__ __align__(16) float lds_attn[C];
    __shared__ __align__(16) float lds_lat[C];
    __shared__ float sh_h[8][C];
    __shared__ float red[4];
    __shared__ float wacc[NW][C];
    __shared__ float wm[NW], wd[NW];
    __shared__ int s_lo, s_hi;

    // ---- phase 0: init sentinels + vectorized latent load ----
    if (tid == 0) { s_lo = (g == 0) ? 0 : -1; s_hi = (g == B - 1) ? n : -1; }
    if (tid < 32)
        *(f32x4*)&lds_lat[tid * 4] =
            *(const f32x4*)&latent[(size_t)g * C + tid * 4];
    __syncthreads();

    // ---- phase 1: window scan + GEMV partials (independent work) ----
    {
        const int center = g * (n / B) + (n / B) / 2;
        int wbase = center - WIN / 2;
        if (wbase < 1) wbase = 1;
        #pragma unroll
        for (int k = 0; k < WIN / NT; ++k) {
            int i = wbase + tid + k * NT;
            if (i < n) {
                int gi = groups[i];
                int gp = groups[i - 1];
                if (gp < g && g <= gi) s_lo = i;         // unique writer
                if (gp < g + 1 && g + 1 <= gi) s_hi = i; // unique writer
            }
        }
    }
    {
        const int c = tid & (C - 1);
        const int seg = tid >> 7;            // 0..7, 16 inputs each
        float hp = 0.f;
        #pragma unroll
        for (int in = seg * 16; in < seg * 16 + 16; ++in)
            hp = fmaf(lds_lat[in], f1_w[in * C + c], hp);
        sh_h[seg][c] = hp;
    }
    __syncthreads();

    // fallback: window missed (distribution-independent correctness)
    if (s_lo < 0 || s_hi < 0) {
        for (int i = 1 + tid; i < n; i += NT) {
            int gi = groups[i];
            int gp = groups[i - 1];
            if (gp < g && g <= gi) s_lo = i;
            if (gp < g + 1 && g + 1 <= gi) s_hi = i;
        }
        __syncthreads();
        if (tid == 0) {
            if (s_lo < 0) s_lo = (groups[0] >= g) ? 0 : n;
            if (s_hi < 0) s_hi = (groups[0] >= g + 1) ? 0 : n;
        }
        __syncthreads();
    }

    const int lo = s_lo, hi = s_hi;

    const int half = lane >> 5;   // which of the 2 rows this half-wave covers
    const int cl = lane & 31;     // channel-lane: channels 4*cl..4*cl+3

    // ---- phase 2a: ISSUE first stream tile (overlaps attnv finalize) ----
    int base = lo + wv * 8;
    f32x4 r[4];
    if (base < hi) {
        #pragma unroll
        for (int j = 0; j < 4; ++j) {
            int row = base + 2 * j + half;
            int rc = row < hi ? row : (hi - 1);
            r[j] = *(const f32x4*)&node[(size_t)rc * C + cl * 4];
        }
    }

    // ---- phase 2b: finalize attn_vec ----
    if (tid < C) {
        float h = sh_h[0][tid] + sh_h[1][tid] + sh_h[2][tid] + sh_h[3][tid]
                + sh_h[4][tid] + sh_h[5][tid] + sh_h[6][tid] + sh_h[7][tid]
                + f1_b[tid];
        h = fmaxf(h, 0.f);
        float fp = h * f2_w[tid];
        float ap = node[(size_t)g * C + tid] * w_w[tid];
        #pragma unroll
        for (int off = 32; off >= 1; off >>= 1) {
            ap += __shfl_xor(ap, off);
            fp += __shfl_xor(fp, off);
        }
        if (lane == 0) { red[wv * 2] = ap; red[wv * 2 + 1] = fp; }
    }
    __syncthreads();
    if (tid < C) {
        float a_sum = red[0] + red[2];
        float f_sum = red[1] + red[3];
        float alpha = 1.f / (1.f + __expf(-(a_sum + w_b[0])));
        float fout = f_sum + f2_b[0];
        lds_attn[tid] = alpha * fout + (1.f - alpha) * attn_w[tid];
    }
    __syncthreads();

    const f32x4 av = *(const f32x4*)&lds_attn[cl * 4];

    // ---- main: rotated streaming loop (r holds current tile) ----
    float m = -INFINITY, denom = 0.f;
    f32x4 acc = (f32x4)(0.f);

    for (; base < hi; ) {
        float s[4];
        #pragma unroll
        for (int j = 0; j < 4; ++j)
            s[j] = fmaf(r[j].x, av.x, fmaf(r[j].y, av.y,
                    fmaf(r[j].z, av.z, r[j].w * av.w)));

        // multi-row butterfly reduce: 4 partials over each 32-lane half.
        float k0, k1;
        {
            float ka = (lane & 1) ? s[1] : s[0];
            float sa = (lane & 1) ? s[0] : s[1];
            float kb = (lane & 1) ? s[3] : s[2];
            float sb = (lane & 1) ? s[2] : s[3];
            k0 = ka + __shfl_xor(sa, 1);
            k1 = kb + __shfl_xor(sb, 1);
        }
        float k;
        {
            float ka = (lane & 2) ? k1 : k0;
            float sa = (lane & 2) ? k0 : k1;
            k = ka + __shfl_xor(sa, 2);
        }
        k += __shfl_xor(k, 4);
        k += __shfl_xor(k, 8);
        k += __shfl_xor(k, 16);
        // k = full dot of row (base + 2*(lane&3) + half)
        int rown = base + 2 * (lane & 3) + half;
        k = (rown < hi) ? k : -INFINITY;

        // row max over the 8 distinct rows (bits 0,1,5)
        float mx = k;
        mx = fmaxf(mx, __shfl_xor(mx, 1));
        mx = fmaxf(mx, __shfl_xor(mx, 2));
        mx = fmaxf(mx, __shfl_xor(mx, 32));
        float mb = fmaxf(m, mx);
        float scale = __expf(m - mb);   // m=-inf -> 0, correct
        float p = __expf(k - mb);       // k=-inf -> 0

        float ps = p;
        ps += __shfl_xor(ps, 1);
        ps += __shfl_xor(ps, 2);
        ps += __shfl_xor(ps, 32);
        denom = fmaf(denom, scale, ps);

        // broadcast each row's p (compile-time lane -> v_readlane)
        float pe[4], po[4];
        #pragma unroll
        for (int t = 0; t < 4; ++t) {
            pe[t] = __shfl(p, t);        // row base+2t   (half 0)
            po[t] = __shfl(p, 32 + t);   // row base+2t+1 (half 1)
        }
        acc.x *= scale; acc.y *= scale; acc.z *= scale; acc.w *= scale;
        #pragma unroll
        for (int j = 0; j < 4; ++j) {
            float pj = half ? po[j] : pe[j];
            acc.x = fmaf(pj, r[j].x, acc.x);
            acc.y = fmaf(pj, r[j].y, acc.y);
            acc.z = fmaf(pj, r[j].z, acc.z);
            acc.w = fmaf(pj, r[j].w, acc.w);
        }
        m = mb;

        // load next tile (loop rotation)
        base += NW * 8;
        if (base < hi) {
            #pragma unroll
            for (int j = 0; j < 4; ++j) {
                int row = base + 2 * j + half;
                int rc = row < hi ? row : (hi - 1);
                r[j] = *(const f32x4*)&node[(size_t)rc * C + cl * 4];
            }
        }
    }

    // fold the two halves (disjoint row sets, same channels)
    acc.x += __shfl_xor(acc.x, 32);
    acc.y += __shfl_xor(acc.y, 32);
    acc.z += __shfl_xor(acc.z, 32);
    acc.w += __shfl_xor(acc.w, 32);

    if (lane == 0) { wm[wv] = m; wd[wv] = denom; }
    if (lane < 32) {
        wacc[wv][cl * 4 + 0] = acc.x;
        wacc[wv][cl * 4 + 1] = acc.y;
        wacc[wv][cl * 4 + 2] = acc.z;
        wacc[wv][cl * 4 + 3] = acc.w;
    }
    __syncthreads();

    // merge 16 wave states -> out[g] directly
    if (tid < C) {
        float M = -INFINITY;
        #pragma unroll
        for (int w = 0; w < NW; ++w) M = fmaxf(M, wm[w]);
        float D = 0.f, A = 0.f;
        #pragma unroll
        for (int w = 0; w < NW; ++w) {
            float sc = (wm[w] == -INFINITY) ? 0.f : __expf(wm[w] - M);
            D = fmaf(wd[w], sc, D);
            A = fmaf(wacc[w][tid], sc, A);
        }
        out[(size_t)g * C + tid] = (D > 0.f) ? (A / D) : 0.f;
    }
}

extern "C" void kernel_launch(void* const* d_in, const int* in_sizes, int n_in,
                              void* d_out, int out_size, void* d_ws, size_t ws_size,
                              hipStream_t stream) {
    const float* node   = (const float*)d_in[0];
    const float* latent = (const float*)d_in[1];
    const float* attn_w = (const float*)d_in[2];
    const float* w_w    = (const float*)d_in[3];
    const float* w_b    = (const float*)d_in[4];
    const float* f1_w   = (const float*)d_in[5];
    const float* f1_b   = (const float*)d_in[6];
    const float* f2_w   = (const float*)d_in[7];
    const float* f2_b   = (const float*)d_in[8];
    const int*   groups = (const int*)d_in[9];

    const int n = in_sizes[9];        // N nodes
    const int b = in_sizes[1] / C;    // number of graphs

    k_attn<<<b, NT, 0, stream>>>(node, latent, attn_w, w_w, w_b,
                                 f1_w, f1_b, f2_w, f2_b, groups, n,
                                 (float*)d_out);
}

// Round 9
// 48.086 us; speedup vs baseline: 1.3210x; 1.3210x over previous
//
#include <hip/hip_runtime.h>
#include <math.h>

#define C 128
#define NW 16        // waves per block
#define NT 1024      // threads per block
#define WIN 8192     // bounds-scan window (positions); >=10 sigma margin

typedef float f32x4 __attribute__((ext_vector_type(4)));

// Single fused kernel: one 1024-thread block (16 waves) per group.
// Prologue: (1) windowed scan of sorted `groups` for [lo,hi) with full-scan
// fallback; (2) in-block 128x128 GEMV -> attn_vec in LDS; node[g] row load
// issued at phase 0 so its latency hides behind scan+GEMV.
// Main: plain streaming online-softmax loop (R7 structure — compiler
// pipelines it best; explicit rotation regressed 15us in R8).
__global__ __launch_bounds__(NT, 8)
void k_attn(const float* __restrict__ node,
            const float* __restrict__ latent,
            const float* __restrict__ attn_w,
            const float* __restrict__ w_w,
            const float* __restrict__ w_b,
            const float* __restrict__ f1_w,
            const float* __restrict__ f1_b,
            const float* __restrict__ f2_w,
            const float* __restrict__ f2_b,
            const int* __restrict__ groups, int n,
            float* __restrict__ out) {
    const int g = blockIdx.x;
    const int B = gridDim.x;
    const int tid = threadIdx.x;
    const int lane = tid & 63;
    const int wv = tid >> 6;   // 0..15

    __shared__ __align__(16) float lds_attn[C];
    __shared__ __align__(16) float lds_lat[C];
    __shared__ float sh_h[8][C];
    __shared__ float red[4];
    __shared__ float wacc[NW][C];
    __shared__ float wm[NW], wd[NW];
    __shared__ int s_lo, s_hi;

    // ---- phase 0: sentinels + latent load + EARLY node[g] row load ----
    if (tid == 0) { s_lo = (g == 0) ? 0 : -1; s_hi = (g == B - 1) ? n : -1; }
    if (tid < 32)
        *(f32x4*)&lds_lat[tid * 4] =
            *(const f32x4*)&latent[(size_t)g * C + tid * 4];
    float nrow = 0.f;
    if (tid < C) nrow = node[(size_t)g * C + tid];   // latency hidden below
    __syncthreads();

    // ---- phase 1: window scan + GEMV partials (independent work) ----
    {
        const int center = g * (n / B) + (n / B) / 2;
        int wbase = center - WIN / 2;
        if (wbase < 1) wbase = 1;
        #pragma unroll
        for (int k = 0; k < WIN / NT; ++k) {
            int i = wbase + tid + k * NT;
            if (i < n) {
                int gi = groups[i];
                int gp = groups[i - 1];
                if (gp < g && g <= gi) s_lo = i;         // unique writer
                if (gp < g + 1 && g + 1 <= gi) s_hi = i; // unique writer
            }
        }
    }
    {
        const int c = tid & (C - 1);
        const int seg = tid >> 7;            // 0..7, 16 inputs each
        float hp = 0.f;
        #pragma unroll
        for (int in = seg * 16; in < seg * 16 + 16; ++in)
            hp = fmaf(lds_lat[in], f1_w[in * C + c], hp);
        sh_h[seg][c] = hp;
    }
    __syncthreads();

    // fallback: window missed (distribution-independent correctness)
    if (s_lo < 0 || s_hi < 0) {
        for (int i = 1 + tid; i < n; i += NT) {
            int gi = groups[i];
            int gp = groups[i - 1];
            if (gp < g && g <= gi) s_lo = i;
            if (gp < g + 1 && g + 1 <= gi) s_hi = i;
        }
        __syncthreads();
        if (tid == 0) {
            if (s_lo < 0) s_lo = (groups[0] >= g) ? 0 : n;
            if (s_hi < 0) s_hi = (groups[0] >= g + 1) ? 0 : n;
        }
        __syncthreads();
    }

    // ---- phase 2: finalize attn_vec ----
    if (tid < C) {
        float h = sh_h[0][tid] + sh_h[1][tid] + sh_h[2][tid] + sh_h[3][tid]
                + sh_h[4][tid] + sh_h[5][tid] + sh_h[6][tid] + sh_h[7][tid]
                + f1_b[tid];
        h = fmaxf(h, 0.f);
        float fp = h * f2_w[tid];
        float ap = nrow * w_w[tid];
        #pragma unroll
        for (int off = 32; off >= 1; off >>= 1) {
            ap += __shfl_xor(ap, off);
            fp += __shfl_xor(fp, off);
        }
        if (lane == 0) { red[wv * 2] = ap; red[wv * 2 + 1] = fp; }
    }
    __syncthreads();
    if (tid < C) {
        float a_sum = red[0] + red[2];
        float f_sum = red[1] + red[3];
        float alpha = 1.f / (1.f + __expf(-(a_sum + w_b[0])));
        float fout = f_sum + f2_b[0];
        lds_attn[tid] = alpha * fout + (1.f - alpha) * attn_w[tid];
    }
    __syncthreads();

    // ---- main: streaming online-softmax reduction (R7 plain loop) ----
    const int lo = s_lo, hi = s_hi;

    const int half = lane >> 5;   // which of the 2 rows this half-wave covers
    const int cl = lane & 31;     // channel-lane: channels 4*cl..4*cl+3
    const f32x4 av = *(const f32x4*)&lds_attn[cl * 4];

    float m = -INFINITY, denom = 0.f;
    f32x4 acc = (f32x4)(0.f);

    for (int base = lo + wv * 8; base < hi; base += NW * 8) {
        f32x4 r[4];
        #pragma unroll
        for (int j = 0; j < 4; ++j) {
            int row = base + 2 * j + half;
            int rc = row < hi ? row : (hi - 1);   // clamp; masked below
            r[j] = *(const f32x4*)&node[(size_t)rc * C + cl * 4];
        }
        float s[4];
        #pragma unroll
        for (int j = 0; j < 4; ++j)
            s[j] = fmaf(r[j].x, av.x, fmaf(r[j].y, av.y,
                    fmaf(r[j].z, av.z, r[j].w * av.w)));

        // multi-row butterfly reduce: 4 partials over each 32-lane half.
        float k0, k1;
        {
            float ka = (lane & 1) ? s[1] : s[0];
            float sa = (lane & 1) ? s[0] : s[1];
            float kb = (lane & 1) ? s[3] : s[2];
            float sb = (lane & 1) ? s[2] : s[3];
            k0 = ka + __shfl_xor(sa, 1);
            k1 = kb + __shfl_xor(sb, 1);
        }
        float k;
        {
            float ka = (lane & 2) ? k1 : k0;
            float sa = (lane & 2) ? k0 : k1;
            k = ka + __shfl_xor(sa, 2);
        }
        k += __shfl_xor(k, 4);
        k += __shfl_xor(k, 8);
        k += __shfl_xor(k, 16);
        // k = full dot of row (base + 2*(lane&3) + half)
        int rown = base + 2 * (lane & 3) + half;
        k = (rown < hi) ? k : -INFINITY;

        // row max over the 8 distinct rows (bits 0,1,5)
        float mx = k;
        mx = fmaxf(mx, __shfl_xor(mx, 1));
        mx = fmaxf(mx, __shfl_xor(mx, 2));
        mx = fmaxf(mx, __shfl_xor(mx, 32));
        float mb = fmaxf(m, mx);
        float scale = __expf(m - mb);   // m=-inf -> 0, correct
        float p = __expf(k - mb);       // k=-inf -> 0

        float ps = p;
        ps += __shfl_xor(ps, 1);
        ps += __shfl_xor(ps, 2);
        ps += __shfl_xor(ps, 32);
        denom = fmaf(denom, scale, ps);

        // broadcast each row's p (compile-time lane -> v_readlane)
        float pe[4], po[4];
        #pragma unroll
        for (int t = 0; t < 4; ++t) {
            pe[t] = __shfl(p, t);        // row base+2t   (half 0)
            po[t] = __shfl(p, 32 + t);   // row base+2t+1 (half 1)
        }
        acc.x *= scale; acc.y *= scale; acc.z *= scale; acc.w *= scale;
        #pragma unroll
        for (int j = 0; j < 4; ++j) {
            float pj = half ? po[j] : pe[j];
            acc.x = fmaf(pj, r[j].x, acc.x);
            acc.y = fmaf(pj, r[j].y, acc.y);
            acc.z = fmaf(pj, r[j].z, acc.z);
            acc.w = fmaf(pj, r[j].w, acc.w);
        }
        m = mb;
    }

    // fold the two halves (disjoint row sets, same channels)
    acc.x += __shfl_xor(acc.x, 32);
    acc.y += __shfl_xor(acc.y, 32);
    acc.z += __shfl_xor(acc.z, 32);
    acc.w += __shfl_xor(acc.w, 32);

    if (lane == 0) { wm[wv] = m; wd[wv] = denom; }
    if (lane < 32) {
        wacc[wv][cl * 4 + 0] = acc.x;
        wacc[wv][cl * 4 + 1] = acc.y;
        wacc[wv][cl * 4 + 2] = acc.z;
        wacc[wv][cl * 4 + 3] = acc.w;
    }
    __syncthreads();

    // merge 16 wave states -> out[g] directly
    if (tid < C) {
        float M = -INFINITY;
        #pragma unroll
        for (int w = 0; w < NW; ++w) M = fmaxf(M, wm[w]);
        float D = 0.f, A = 0.f;
        #pragma unroll
        for (int w = 0; w < NW; ++w) {
            float sc = (wm[w] == -INFINITY) ? 0.f : __expf(wm[w] - M);
            D = fmaf(wd[w], sc, D);
            A = fmaf(wacc[w][tid], sc, A);
        }
        out[(size_t)g * C + tid] = (D > 0.f) ? (A / D) : 0.f;
    }
}

extern "C" void kernel_launch(void* const* d_in, const int* in_sizes, int n_in,
                              void* d_out, int out_size, void* d_ws, size_t ws_size,
                              hipStream_t stream) {
    const float* node   = (const float*)d_in[0];
    const float* latent = (const float*)d_in[1];
    const float* attn_w = (const float*)d_in[2];
    const float* w_w    = (const float*)d_in[3];
    const float* w_b    = (const float*)d_in[4];
    const float* f1_w   = (const float*)d_in[5];
    const float* f1_b   = (const float*)d_in[6];
    const float* f2_w   = (const float*)d_in[7];
    const float* f2_b   = (const float*)d_in[8];
    const int*   groups = (const int*)d_in[9];

    const int n = in_sizes[9];        // N nodes
    const int b = in_sizes[1] / C;    // number of graphs

    k_attn<<<b, NT, 0, stream>>>(node, latent, attn_w, w_w, w_b,
                                 f1_w, f1_b, f2_w, f2_b, groups, n,
                                 (float*)d_out);
}